// Round 16
// baseline (212.271 us; speedup 1.0000x reference)
//
#include <hip/hip_runtime.h>
#include <hip/hip_bf16.h>

#define NV 512
#define NB 128
#define NC 64

typedef float fv4 __attribute__((ext_vector_type(4)));
typedef float fv2 __attribute__((ext_vector_type(2)));
typedef float f32x4 __attribute__((ext_vector_type(4)));
typedef short bf8 __attribute__((ext_vector_type(8)));            // 8 bf16 (MFMA A/B frag)
typedef unsigned short u16x4 __attribute__((ext_vector_type(4)));
typedef unsigned short u16x8 __attribute__((ext_vector_type(8)));
typedef unsigned u32x2 __attribute__((ext_vector_type(2)));
typedef unsigned u32x4 __attribute__((ext_vector_type(4)));

// f32 -> bf16 RNE, scalar
__device__ __forceinline__ unsigned short f2bf(float f) {
  unsigned u = __builtin_bit_cast(unsigned, f);
  u += 0x7fffu + ((u >> 16) & 1u);
  return (unsigned short)(u >> 16);
}

// packed f32x2 -> bf16x2 (v_cvt_pk_bf16_f32)
__device__ __forceinline__ unsigned cvt2(float lo, float hi) {
  __hip_bfloat162 h = __float22bfloat162_rn(make_float2(lo, hi));
  unsigned r;
  __builtin_memcpy(&r, &h, sizeof(r));
  return r;
}

__device__ __forceinline__ bf8 pack8(fv4 a0, fv4 a1) {
  u32x4 r;
  r[0] = cvt2(a0[0], a0[1]);
  r[1] = cvt2(a0[2], a0[3]);
  r[2] = cvt2(a1[0], a1[1]);
  r[3] = cvt2(a1[2], a1[3]);
  return __builtin_bit_cast(bf8, r);
}

// panel: [cols][512 rows] bf16, 1KB per col; XOR swizzle on 16B granules
__device__ __forceinline__ int swzL(int c, int r) {
  return ((c << 10) + (r << 1)) ^ ((c & 7) << 4);
}
// fallback staging layout
__device__ __forceinline__ int swzC(int j, int ii) {
  return ((j << 6) + (ii << 1)) ^ ((j & 3) << 4);
}

__device__ __forceinline__ void gload_lds16(const void* g, void* l) {
  __builtin_amdgcn_global_load_lds(
      (const __attribute__((address_space(1))) unsigned int*)g,
      (__attribute__((address_space(3))) unsigned int*)l, 16, 0, 0);
}

// ---------------------------------------------------------------------------
// Convert kernels
// ---------------------------------------------------------------------------
__global__ __launch_bounds__(256, 4)
void conv_f32_bf16_kernel(const float* __restrict__ src, unsigned short* __restrict__ dst) {
  const size_t i8 = ((size_t)blockIdx.x * 256 + threadIdx.x) * 8;
  fv4 a0 = *(const fv4*)(src + i8);
  fv4 a1 = *(const fv4*)(src + i8 + 4);
  u32x4 r;
  r[0] = cvt2(a0[0], a0[1]); r[1] = cvt2(a0[2], a0[3]);
  r[2] = cvt2(a1[0], a1[1]); r[3] = cvt2(a1[2], a1[3]);
  *(u32x4*)(dst + i8) = r;
}

// chol f32 -> LR bf16 (row-major, optional) + LT bf16 (transposed)
__global__ __launch_bounds__(256, 4)
void convert_LT_kernel(const float* __restrict__ chol,
                       unsigned short* __restrict__ LT,
                       unsigned short* __restrict__ LR) {
  __shared__ unsigned short T[64][72];
  const int bid = blockIdx.x;
  const int b  = bid >> 6;
  const int t  = bid & 63;
  const int ti = t >> 3, tj = t & 7;

  const float* src = chol + ((size_t)b * NV + ti * 64) * NV + tj * 64;
  {
    const int r0 = threadIdx.x >> 4;
    const int c4 = (threadIdx.x & 15) * 4;
    #pragma unroll
    for (int p = 0; p < 4; ++p) {
      const int r = p * 16 + r0;
      fv4 v = *(const fv4*)(src + (size_t)r * NV + c4);
      T[c4 + 0][r] = f2bf(v[0]);
      T[c4 + 1][r] = f2bf(v[1]);
      T[c4 + 2][r] = f2bf(v[2]);
      T[c4 + 3][r] = f2bf(v[3]);
      if (LR) {
        u32x2 pk; pk[0] = cvt2(v[0], v[1]); pk[1] = cvt2(v[2], v[3]);
        *(u32x2*)(LR + ((size_t)b * NV + ti * 64 + r) * NV + tj * 64 + c4) = pk;
      }
    }
  }
  __syncthreads();
  unsigned short* dst = LT + ((size_t)b * NV + tj * 64) * NV + ti * 64;
  const int c  = threadIdx.x >> 2;
  const int k8 = (threadIdx.x & 3) * 16;
  u16x8 o0, o1;
  #pragma unroll
  for (int q = 0; q < 8; ++q) { o0[q] = T[c][k8 + q]; o1[q] = T[c][k8 + 8 + q]; }
  *(u16x8*)(dst + (size_t)c * NV + k8)     = o0;
  *(u16x8*)(dst + (size_t)c * NV + k8 + 8) = o1;
}

// ---------------------------------------------------------------------------
// v11 main kernel: v10 + (a) bank-conflict-free A-buffer via both-sides
// kq-swizzle (kq ^ ((row>>1)&3)) — DMA source pre-swizzled, LDS linear,
// read applies the same XOR; (b) s_setprio(1) around the MFMA cluster.
// ---------------------------------------------------------------------------
__device__ __forceinline__ void stageA11(const unsigned short* A, int t, char* buf,
                                         int w, int lane) {
  const int row = lane >> 2;                       // 0..15 within 16-row chunk
  const int kq  = (lane & 3) ^ ((row >> 1) & 3);   // pre-swizzled source quarter
  #pragma unroll
  for (int pi = 0; pi < 4; ++pi) {
    const unsigned short* src = A + (size_t)(w * 64 + pi * 16 + row) * NV + t * 32 + kq * 8;
    gload_lds16(src, buf + pi * 1024);
  }
}

__device__ __forceinline__ void phase_v11(const unsigned short* Abase,
                                          const char* H, char* buf,
                                          f32x4 (&acc0)[4][4], f32x4 (&acc1)[4][4],
                                          int w, int lane, int lr, int lq) {
  stageA11(Abase, 0, buf, w, lane);
  #pragma unroll 2
  for (int t = 0; t < 16; ++t) {
    const int kbase = t * 32 + lq * 8;
    // wait own DMA (per-wave; no barrier)
    asm volatile("s_waitcnt vmcnt(0)" ::: "memory");
    bf8 a[4];
    const int kqr = (lq ^ ((lr >> 1) & 3)) * 16;   // read-side swizzle
    #pragma unroll
    for (int m = 0; m < 4; ++m)
      a[m] = *(const bf8*)(buf + (m * 16 + lr) * 64 + kqr);
    // issue next tile's DMA: after the A ds_reads, before the MFMA block
    if (t + 1 < 16) stageA11(Abase, t + 1, buf, w, lane);
    bf8 b0[4];
    #pragma unroll
    for (int n = 0; n < 4; ++n)
      b0[n] = *(const bf8*)(H + swzL(n * 16 + lr, kbase));
    bf8 b1[4];
    #pragma unroll
    for (int n = 0; n < 4; ++n)
      b1[n] = *(const bf8*)(H + swzL(64 + n * 16 + lr, kbase));
    __builtin_amdgcn_s_setprio(1);
    #pragma unroll
    for (int m = 0; m < 4; ++m)
      #pragma unroll
      for (int n = 0; n < 4; ++n)
        acc0[m][n] = __builtin_amdgcn_mfma_f32_16x16x32_bf16(a[m], b0[n], acc0[m][n], 0, 0, 0);
    #pragma unroll
    for (int m = 0; m < 4; ++m)
      #pragma unroll
      for (int n = 0; n < 4; ++n)
        acc1[m][n] = __builtin_amdgcn_mfma_f32_16x16x32_bf16(a[m], b1[n], acc1[m][n], 0, 0, 0);
    __builtin_amdgcn_s_setprio(0);
  }
}

__global__ __launch_bounds__(512, 2)
void fused_cholTE_v11(const unsigned short* __restrict__ CV,
                      const unsigned short* __restrict__ LR,
                      const unsigned short* __restrict__ LT,
                      float* __restrict__ out) {
  __shared__ __align__(16) char lds[163840];
  char* H = lds;                          // 128 cols x 1KB: cholC -> T1 -> phi

  const int tid  = threadIdx.x;
  const int w    = tid >> 6;              // wave 0..7
  const int lane = tid & 63;
  const int lr   = lane & 15;
  const int lq   = lane >> 4;
  char* buf = lds + 131072 + w * 4096;    // private per-wave A buffer

  const int bid = blockIdx.x;
  const int xcd = bid & 7;
  const int s   = bid >> 3;               // 0..63
  const int b   = xcd * 16 + (s >> 2);    // batch
  const int c0  = (s & 3) * 128;          // column pair base

  const unsigned short* CVb = CV + (size_t)b * NV * NV;
  const unsigned short* LRb = LR + (size_t)b * NV * NV;
  const unsigned short* LTb = LT + (size_t)b * NV * NV;
  float*                Ob  = out + (size_t)b * NV * NV;

  f32x4 acc0[4][4], acc1[4][4];

  // ---- stage both cholC panels: LT rows c0..c0+127 -> H (source-swizzled)
  #pragma unroll
  for (int cc = 0; cc < 16; ++cc) {
    const int c = cc * 8 + w;
    const unsigned short* src = LTb + (size_t)(c0 + c) * NV + ((lane ^ (c & 7)) * 8);
    gload_lds16(src, H + c * 1024);
  }
  asm volatile("s_waitcnt vmcnt(0)" ::: "memory");
  __syncthreads();   // barrier 1: cholC panels ready

  // ---- Phase B: T1 = CV @ cholC
  #pragma unroll
  for (int m = 0; m < 4; ++m)
    #pragma unroll
    for (int n = 0; n < 4; ++n) { acc0[m][n] = (f32x4)0.f; acc1[m][n] = (f32x4)0.f; }
  phase_v11(CVb, H, buf, acc0, acc1, w, lane, lr, lq);
  __syncthreads();   // barrier 2: done reading cholC

  // T1 -> H (overwrite)
  #pragma unroll
  for (int m = 0; m < 4; ++m) {
    #pragma unroll
    for (int n = 0; n < 4; ++n) {
      const int rrow = w * 64 + m * 16 + lq * 4;
      f32x4 a = acc0[m][n];
      u32x2 pk; pk[0] = cvt2(a[0], a[1]); pk[1] = cvt2(a[2], a[3]);
      *(u32x2*)(H + swzL(n * 16 + lr, rrow)) = pk;
      a = acc1[m][n];
      pk[0] = cvt2(a[0], a[1]); pk[1] = cvt2(a[2], a[3]);
      *(u32x2*)(H + swzL(64 + n * 16 + lr, rrow)) = pk;
    }
  }
  __syncthreads();   // barrier 3: T1 panels ready

  // ---- Phase C: phi = LT-rows @ T1 (masked)
  #pragma unroll
  for (int m = 0; m < 4; ++m)
    #pragma unroll
    for (int n = 0; n < 4; ++n) { acc0[m][n] = (f32x4)0.f; acc1[m][n] = (f32x4)0.f; }
  phase_v11(LTb, H, buf, acc0, acc1, w, lane, lr, lq);
  __syncthreads();   // barrier 4: done reading T1

  // mask (strict lower=1, diag=0.5, upper=0); phi -> H (overwrite)
  #pragma unroll
  for (int jt = 0; jt < 4; ++jt) {
    #pragma unroll
    for (int n = 0; n < 4; ++n) {
      const int j0 = w * 64 + jt * 16 + lq * 4;
      const int gk0 = c0 + n * 16 + lr;
      const int gk1 = gk0 + 64;
      f32x4 a = acc0[jt][n];
      float f[4];
      #pragma unroll
      for (int q = 0; q < 4; ++q) {
        const int j = j0 + q;
        f[q] = (j > gk0) ? a[q] : ((j == gk0) ? 0.5f * a[q] : 0.f);
      }
      u32x2 pk; pk[0] = cvt2(f[0], f[1]); pk[1] = cvt2(f[2], f[3]);
      *(u32x2*)(H + swzL(n * 16 + lr, j0)) = pk;
      a = acc1[jt][n];
      #pragma unroll
      for (int q = 0; q < 4; ++q) {
        const int j = j0 + q;
        f[q] = (j > gk1) ? a[q] : ((j == gk1) ? 0.5f * a[q] : 0.f);
      }
      pk[0] = cvt2(f[0], f[1]); pk[1] = cvt2(f[2], f[3]);
      *(u32x2*)(H + swzL(64 + n * 16 + lr, j0)) = pk;
    }
  }
  __syncthreads();   // barrier 5: phi panels ready

  // ---- Phase D: out = -LR @ phi
  #pragma unroll
  for (int m = 0; m < 4; ++m)
    #pragma unroll
    for (int n = 0; n < 4; ++n) { acc0[m][n] = (f32x4)0.f; acc1[m][n] = (f32x4)0.f; }
  phase_v11(LRb, H, buf, acc0, acc1, w, lane, lr, lq);

  #pragma unroll
  for (int m = 0; m < 4; ++m) {
    const int i0 = w * 64 + m * 16 + lq * 4;
    #pragma unroll
    for (int n = 0; n < 4; ++n) {
      const int col = c0 + n * 16 + lr;
      f32x4 a = acc0[m][n];
      #pragma unroll
      for (int q = 0; q < 4; ++q)
        Ob[(size_t)(i0 + q) * NV + col] = -a[q];
      a = acc1[m][n];
      #pragma unroll
      for (int q = 0; q < 4; ++q)
        Ob[(size_t)(i0 + q) * NV + col + 64] = -a[q];
    }
  }
}

// ---------------------------------------------------------------------------
// v9 (LT-only path) for 64MB <= ws < 192MB
// ---------------------------------------------------------------------------
__device__ __forceinline__ void phase_v9_f32(const float* Abase,
                                             const char* H,
                                             f32x4 (&acc0)[4][4], f32x4 (&acc1)[4][4],
                                             int w, int lr, int lq) {
  const float* rA = Abase + (size_t)(w * 64 + lr) * NV + lq * 8;
  #pragma unroll 2
  for (int t = 0; t < 16; ++t) {
    const int kbase = t * 32 + lq * 8;
    bf8 a[4];
    #pragma unroll
    for (int m = 0; m < 4; ++m) {
      fv4 f0 = *(const fv4*)(rA + (size_t)(m * 16) * NV + t * 32);
      fv4 f1 = *(const fv4*)(rA + (size_t)(m * 16) * NV + t * 32 + 4);
      a[m] = pack8(f0, f1);
    }
    bf8 b0[4];
    #pragma unroll
    for (int n = 0; n < 4; ++n)
      b0[n] = *(const bf8*)(H + swzL(n * 16 + lr, kbase));
    #pragma unroll
    for (int m = 0; m < 4; ++m)
      #pragma unroll
      for (int n = 0; n < 4; ++n)
        acc0[m][n] = __builtin_amdgcn_mfma_f32_16x16x32_bf16(a[m], b0[n], acc0[m][n], 0, 0, 0);
    bf8 b1[4];
    #pragma unroll
    for (int n = 0; n < 4; ++n)
      b1[n] = *(const bf8*)(H + swzL(64 + n * 16 + lr, kbase));
    #pragma unroll
    for (int m = 0; m < 4; ++m)
      #pragma unroll
      for (int n = 0; n < 4; ++n)
        acc1[m][n] = __builtin_amdgcn_mfma_f32_16x16x32_bf16(a[m], b1[n], acc1[m][n], 0, 0, 0);
  }
}

__device__ __forceinline__ void phase_v9_bf16(const unsigned short* Abase,
                                              const char* H,
                                              f32x4 (&acc0)[4][4], f32x4 (&acc1)[4][4],
                                              int w, int lr, int lq) {
  const unsigned short* rA = Abase + (size_t)(w * 64 + lr) * NV + lq * 8;
  #pragma unroll 2
  for (int t = 0; t < 16; ++t) {
    const int kbase = t * 32 + lq * 8;
    bf8 a[4];
    #pragma unroll
    for (int m = 0; m < 4; ++m)
      a[m] = *(const bf8*)(rA + (size_t)(m * 16) * NV + t * 32);
    bf8 b0[4];
    #pragma unroll
    for (int n = 0; n < 4; ++n)
      b0[n] = *(const bf8*)(H + swzL(n * 16 + lr, kbase));
    #pragma unroll
    for (int m = 0; m < 4; ++m)
      #pragma unroll
      for (int n = 0; n < 4; ++n)
        acc0[m][n] = __builtin_amdgcn_mfma_f32_16x16x32_bf16(a[m], b0[n], acc0[m][n], 0, 0, 0);
    bf8 b1[4];
    #pragma unroll
    for (int n = 0; n < 4; ++n)
      b1[n] = *(const bf8*)(H + swzL(64 + n * 16 + lr, kbase));
    #pragma unroll
    for (int m = 0; m < 4; ++m)
      #pragma unroll
      for (int n = 0; n < 4; ++n)
        acc1[m][n] = __builtin_amdgcn_mfma_f32_16x16x32_bf16(a[m], b1[n], acc1[m][n], 0, 0, 0);
  }
}

__global__ __launch_bounds__(512, 2)
void fused_cholTE_v9(const float* __restrict__ covTE,
                     const float* __restrict__ chol,
                     const unsigned short* __restrict__ LT,
                     float* __restrict__ out) {
  __shared__ __align__(16) char H[131072];

  const int tid  = threadIdx.x;
  const int w    = tid >> 6;
  const int lane = tid & 63;
  const int lr   = lane & 15;
  const int lq   = lane >> 4;

  const int bid = blockIdx.x;
  const int xcd = bid & 7;
  const int s   = bid >> 3;
  const int b   = xcd * 16 + (s >> 2);
  const int c0  = (s & 3) * 128;

  const float*          Cb  = covTE + (size_t)b * NV * NV;
  const float*          Lb  = chol  + (size_t)b * NV * NV;
  const unsigned short* LTb = LT    + (size_t)b * NV * NV;
  float*                Ob  = out   + (size_t)b * NV * NV;

  f32x4 acc0[4][4], acc1[4][4];

  #pragma unroll
  for (int cc = 0; cc < 16; ++cc) {
    const int c = cc * 8 + w;
    const unsigned short* src = LTb + (size_t)(c0 + c) * NV + ((lane ^ (c & 7)) * 8);
    gload_lds16(src, H + c * 1024);
  }
  asm volatile("s_waitcnt vmcnt(0)" ::: "memory");
  __syncthreads();

  #pragma unroll
  for (int m = 0; m < 4; ++m)
    #pragma unroll
    for (int n = 0; n < 4; ++n) { acc0[m][n] = (f32x4)0.f; acc1[m][n] = (f32x4)0.f; }
  phase_v9_f32(Cb, H, acc0, acc1, w, lr, lq);
  __syncthreads();

  #pragma unroll
  for (int m = 0; m < 4; ++m) {
    #pragma unroll
    for (int n = 0; n < 4; ++n) {
      const int rrow = w * 64 + m * 16 + lq * 4;
      f32x4 a = acc0[m][n];
      u32x2 pk; pk[0] = cvt2(a[0], a[1]); pk[1] = cvt2(a[2], a[3]);
      *(u32x2*)(H + swzL(n * 16 + lr, rrow)) = pk;
      a = acc1[m][n];
      pk[0] = cvt2(a[0], a[1]); pk[1] = cvt2(a[2], a[3]);
      *(u32x2*)(H + swzL(64 + n * 16 + lr, rrow)) = pk;
    }
  }
  __syncthreads();

  #pragma unroll
  for (int m = 0; m < 4; ++m)
    #pragma unroll
    for (int n = 0; n < 4; ++n) { acc0[m][n] = (f32x4)0.f; acc1[m][n] = (f32x4)0.f; }
  phase_v9_bf16(LTb, H, acc0, acc1, w, lr, lq);
  __syncthreads();

  #pragma unroll
  for (int jt = 0; jt < 4; ++jt) {
    #pragma unroll
    for (int n = 0; n < 4; ++n) {
      const int j0 = w * 64 + jt * 16 + lq * 4;
      const int gk0 = c0 + n * 16 + lr;
      const int gk1 = gk0 + 64;
      f32x4 a = acc0[jt][n];
      float f[4];
      #pragma unroll
      for (int q = 0; q < 4; ++q) {
        const int j = j0 + q;
        f[q] = (j > gk0) ? a[q] : ((j == gk0) ? 0.5f * a[q] : 0.f);
      }
      u32x2 pk; pk[0] = cvt2(f[0], f[1]); pk[1] = cvt2(f[2], f[3]);
      *(u32x2*)(H + swzL(n * 16 + lr, j0)) = pk;
      a = acc1[jt][n];
      #pragma unroll
      for (int q = 0; q < 4; ++q) {
        const int j = j0 + q;
        f[q] = (j > gk1) ? a[q] : ((j == gk1) ? 0.5f * a[q] : 0.f);
      }
      pk[0] = cvt2(f[0], f[1]); pk[1] = cvt2(f[2], f[3]);
      *(u32x2*)(H + swzL(64 + n * 16 + lr, j0)) = pk;
    }
  }
  __syncthreads();

  #pragma unroll
  for (int m = 0; m < 4; ++m)
    #pragma unroll
    for (int n = 0; n < 4; ++n) { acc0[m][n] = (f32x4)0.f; acc1[m][n] = (f32x4)0.f; }
  phase_v9_f32(Lb, H, acc0, acc1, w, lr, lq);

  #pragma unroll
  for (int m = 0; m < 4; ++m) {
    const int i0 = w * 64 + m * 16 + lq * 4;
    #pragma unroll
    for (int n = 0; n < 4; ++n) {
      const int col = c0 + n * 16 + lr;
      f32x4 a = acc0[m][n];
      #pragma unroll
      for (int q = 0; q < 4; ++q)
        Ob[(size_t)(i0 + q) * NV + col] = -a[q];
      a = acc1[m][n];
      #pragma unroll
      for (int q = 0; q < 4; ++q)
        Ob[(size_t)(i0 + q) * NV + col + 64] = -a[q];
    }
  }
}

// ---------------------------------------------------------------------------
// No-workspace fallback (R1 form)
// ---------------------------------------------------------------------------
__global__ __launch_bounds__(1024, 1)
void fused_cholTE_fallback(const float* __restrict__ covTE,
                           const float* __restrict__ chol,
                           float* __restrict__ out) {
  __shared__ __align__(16) char lds[131072];
  char* sB0 = lds;
  char* sB1 = lds + 65536;
  char* sCh = lds;

  const int tid  = threadIdx.x;
  const int w    = tid >> 6;
  const int lane = tid & 63;
  const int lr   = lane & 15;
  const int lq   = lane >> 4;

  const int bid = blockIdx.x;
  const int xcd = bid & 7;
  const int s   = bid >> 3;
  const int b   = xcd * 16 + (s >> 3);
  const int c0  = (s & 7) * NC;

  const float* Cb = covTE + (size_t)b * NV * NV;
  const float* Lb = chol  + (size_t)b * NV * NV;
  float*       Ob = out   + (size_t)b * NV * NV;

  {
    const int rr = tid >> 4;
    const int cc = (tid & 15) * 4;
    #pragma unroll
    for (int p = 0; p < 8; ++p) {
      const int r = p * 64 + rr;
      fv4 v = *(const fv4*)(Lb + (size_t)r * NV + c0 + cc);
      *(unsigned short*)(sB0 + swzL(cc + 0, r)) = f2bf(v[0]);
      *(unsigned short*)(sB0 + swzL(cc + 1, r)) = f2bf(v[1]);
      *(unsigned short*)(sB0 + swzL(cc + 2, r)) = f2bf(v[2]);
      *(unsigned short*)(sB0 + swzL(cc + 3, r)) = f2bf(v[3]);
    }
  }
  __syncthreads();

  f32x4 acc[2][4];
  #pragma unroll
  for (int m = 0; m < 2; ++m)
    #pragma unroll
    for (int n = 0; n < 4; ++n) acc[m][n] = (f32x4)0.f;

  for (int kb = 0; kb < 16; ++kb) {
    const int kbase = kb * 32 + lq * 8;
    bf8 bfr[4];
    #pragma unroll
    for (int n = 0; n < 4; ++n)
      bfr[n] = *(const bf8*)(sB0 + swzL(n * 16 + lr, kbase));
    #pragma unroll
    for (int m = 0; m < 2; ++m) {
      const float* p = Cb + (size_t)(w * 32 + m * 16 + lr) * NV + kbase;
      fv4 a0 = *(const fv4*)p;
      fv4 a1 = *(const fv4*)(p + 4);
      bf8 af = pack8(a0, a1);
      #pragma unroll
      for (int n = 0; n < 4; ++n)
        acc[m][n] = __builtin_amdgcn_mfma_f32_16x16x32_bf16(af, bfr[n], acc[m][n], 0, 0, 0);
    }
  }
  #pragma unroll
  for (int m = 0; m < 2; ++m) {
    #pragma unroll
    for (int n = 0; n < 4; ++n) {
      f32x4 a = acc[m][n];
      u32x2 pk; pk[0] = cvt2(a[0], a[1]); pk[1] = cvt2(a[2], a[3]);
      *(u32x2*)(sB1 + swzL(n * 16 + lr, w * 32 + m * 16 + lq * 4)) = pk;
    }
  }
  __syncthreads();

  #pragma unroll
  for (int m = 0; m < 2; ++m)
    #pragma unroll
    for (int n = 0; n < 4; ++n) acc[m][n] = (f32x4)0.f;

  const int sj = (tid & 255) * 2;
  const int so = tid >> 8;

  fv2 raw[8];
  {
    const float* src = Lb + (size_t)(so * 8) * NV + sj;
    #pragma unroll
    for (int r = 0; r < 8; ++r) raw[r] = *(const fv2*)(src + (size_t)r * NV);
    u16x8 p0, p1;
    #pragma unroll
    for (int r = 0; r < 8; ++r) { p0[r] = f2bf(raw[r][0]); p1[r] = f2bf(raw[r][1]); }
    *(u16x8*)(sCh + swzC(sj + 0, so * 8)) = p0;
    *(u16x8*)(sCh + swzC(sj + 1, so * 8)) = p1;
  }
  __syncthreads();

  for (int ib = 0; ib < 16; ++ib) {
    if (ib + 1 < 16) {
      const float* src = Lb + (size_t)((ib + 1) * 32 + so * 8) * NV + sj;
      #pragma unroll
      for (int r = 0; r < 8; ++r) raw[r] = *(const fv2*)(src + (size_t)r * NV);
    }
    bf8 bt[4];
    #pragma unroll
    for (int n = 0; n < 4; ++n)
      bt[n] = *(const bf8*)(sB1 + swzL(n * 16 + lr, ib * 32 + lq * 8));
    #pragma unroll
    for (int jt = 0; jt < 2; ++jt) {
      bf8 af = *(const bf8*)(sCh + swzC(w * 32 + jt * 16 + lr, lq * 8));
      #pragma unroll
      for (int n = 0; n < 4; ++n)
        acc[jt][n] = __builtin_amdgcn_mfma_f32_16x16x32_bf16(af, bt[n], acc[jt][n], 0, 0, 0);
    }
    __syncthreads();
    if (ib + 1 < 16) {
      u16x8 p0, p1;
      #pragma unroll
      for (int r = 0; r < 8; ++r) { p0[r] = f2bf(raw[r][0]); p1[r] = f2bf(raw[r][1]); }
      *(u16x8*)(sCh + swzC(sj + 0, so * 8)) = p0;
      *(u16x8*)(sCh + swzC(sj + 1, so * 8)) = p1;
    }
    __syncthreads();
  }

  #pragma unroll
  for (int jt = 0; jt < 2; ++jt) {
    #pragma unroll
    for (int n = 0; n < 4; ++n) {
      f32x4 a = acc[jt][n];
      const int gk = c0 + n * 16 + lr;
      const int j0 = w * 32 + jt * 16 + lq * 4;
      float f[4];
      #pragma unroll
      for (int q = 0; q < 4; ++q) {
        const int j = j0 + q;
        f[q] = (j > gk) ? a[q] : ((j == gk) ? 0.5f * a[q] : 0.f);
      }
      u32x2 pk; pk[0] = cvt2(f[0], f[1]); pk[1] = cvt2(f[2], f[3]);
      *(u32x2*)(sB0 + swzL(n * 16 + lr, j0)) = pk;
    }
  }
  __syncthreads();

  #pragma unroll
  for (int m = 0; m < 2; ++m)
    #pragma unroll
    for (int n = 0; n < 4; ++n) acc[m][n] = (f32x4)0.f;

  for (int kb = 0; kb < 16; ++kb) {
    const int kbase = kb * 32 + lq * 8;
    bf8 bp[4];
    #pragma unroll
    for (int n = 0; n < 4; ++n)
      bp[n] = *(const bf8*)(sB0 + swzL(n * 16 + lr, kbase));
    #pragma unroll
    for (int m = 0; m < 2; ++m) {
      const float* p = Lb + (size_t)(w * 32 + m * 16 + lr) * NV + kbase;
      fv4 a0 = *(const fv4*)p;
      fv4 a1 = *(const fv4*)(p + 4);
      bf8 af = pack8(a0, a1);
      #pragma unroll
      for (int n = 0; n < 4; ++n)
        acc[m][n] = __builtin_amdgcn_mfma_f32_16x16x32_bf16(af, bp[n], acc[m][n], 0, 0, 0);
    }
  }
  #pragma unroll
  for (int m = 0; m < 2; ++m) {
    const int i0 = w * 32 + m * 16 + lq * 4;
    #pragma unroll
    for (int n = 0; n < 4; ++n) {
      f32x4 a = acc[m][n];
      const int col = c0 + n * 16 + lr;
      #pragma unroll
      for (int q = 0; q < 4; ++q)
        Ob[(size_t)(i0 + q) * NV + col] = -a[q];
    }
  }
}

extern "C" void kernel_launch(void* const* d_in, const int* in_sizes, int n_in,
                              void* d_out, int out_size, void* d_ws, size_t ws_size,
                              hipStream_t stream) {
  const float* muTE  = (const float*)d_in[0];
  const float* covTE = (const float*)d_in[1];
  const float* chol  = (const float*)d_in[2];
  float* out = (float*)d_out;

  (void)hipMemcpyAsync(out, muTE, (size_t)NB * NV * sizeof(float),
                       hipMemcpyDeviceToDevice, stream);

  float* cholTE = out + (size_t)NB * NV;
  const size_t nmat     = (size_t)NB * NV * NV;          // 33,554,432 elems
  const size_t lt_bytes = nmat * sizeof(unsigned short); // 64 MiB

  if (ws_size >= 3 * lt_bytes) {
    unsigned short* CV = (unsigned short*)d_ws;
    unsigned short* LR = CV + nmat;
    unsigned short* LT = LR + nmat;
    conv_f32_bf16_kernel<<<dim3(nmat / (256 * 8)), dim3(256), 0, stream>>>(covTE, CV);
    convert_LT_kernel<<<dim3(NB * 64), dim3(256), 0, stream>>>(chol, LT, LR);
    fused_cholTE_v11<<<dim3(NB * 4), dim3(512), 0, stream>>>(CV, LR, LT, cholTE);
  } else if (ws_size >= lt_bytes) {
    unsigned short* LT = (unsigned short*)d_ws;
    convert_LT_kernel<<<dim3(NB * 64), dim3(256), 0, stream>>>(chol, LT, nullptr);
    fused_cholTE_v9<<<dim3(NB * 4), dim3(512), 0, stream>>>(covTE, chol, LT, cholTE);
  } else {
    fused_cholTE_fallback<<<dim3(NB * (NV / NC)), dim3(1024), 0, stream>>>(
        covTE, chol, cholTE);
  }
}

// Round 19
// 211.954 us; speedup vs baseline: 1.0015x; 1.0015x over previous
//
#include <hip/hip_runtime.h>
#include <hip/hip_bf16.h>

#define NV 512
#define NB 128
#define NC 64

typedef float fv4 __attribute__((ext_vector_type(4)));
typedef float fv2 __attribute__((ext_vector_type(2)));
typedef float f32x4 __attribute__((ext_vector_type(4)));
typedef short bf8 __attribute__((ext_vector_type(8)));            // 8 bf16 (MFMA A/B frag)
typedef unsigned short u16x4 __attribute__((ext_vector_type(4)));
typedef unsigned short u16x8 __attribute__((ext_vector_type(8)));
typedef unsigned u32x2 __attribute__((ext_vector_type(2)));
typedef unsigned u32x4 __attribute__((ext_vector_type(4)));

// f32 -> bf16 RNE, scalar
__device__ __forceinline__ unsigned short f2bf(float f) {
  unsigned u = __builtin_bit_cast(unsigned, f);
  u += 0x7fffu + ((u >> 16) & 1u);
  return (unsigned short)(u >> 16);
}

// packed f32x2 -> bf16x2 (v_cvt_pk_bf16_f32)
__device__ __forceinline__ unsigned cvt2(float lo, float hi) {
  __hip_bfloat162 h = __float22bfloat162_rn(make_float2(lo, hi));
  unsigned r;
  __builtin_memcpy(&r, &h, sizeof(r));
  return r;
}

__device__ __forceinline__ bf8 pack8(fv4 a0, fv4 a1) {
  u32x4 r;
  r[0] = cvt2(a0[0], a0[1]);
  r[1] = cvt2(a0[2], a0[3]);
  r[2] = cvt2(a1[0], a1[1]);
  r[3] = cvt2(a1[2], a1[3]);
  return __builtin_bit_cast(bf8, r);
}

// panel: [cols][512 rows] bf16, 1KB per col; XOR swizzle on 16B granules
__device__ __forceinline__ int swzL(int c, int r) {
  return ((c << 10) + (r << 1)) ^ ((c & 7) << 4);
}
// fallback staging layout
__device__ __forceinline__ int swzC(int j, int ii) {
  return ((j << 6) + (ii << 1)) ^ ((j & 3) << 4);
}

__device__ __forceinline__ void gload_lds16(const void* g, void* l) {
  __builtin_amdgcn_global_load_lds(
      (const __attribute__((address_space(1))) unsigned int*)g,
      (__attribute__((address_space(3))) unsigned int*)l, 16, 0, 0);
}

// ---------------------------------------------------------------------------
// Convert kernels
// ---------------------------------------------------------------------------
__global__ __launch_bounds__(256, 4)
void conv_f32_bf16_kernel(const float* __restrict__ src, unsigned short* __restrict__ dst) {
  const size_t i8 = ((size_t)blockIdx.x * 256 + threadIdx.x) * 8;
  fv4 a0 = *(const fv4*)(src + i8);
  fv4 a1 = *(const fv4*)(src + i8 + 4);
  u32x4 r;
  r[0] = cvt2(a0[0], a0[1]); r[1] = cvt2(a0[2], a0[3]);
  r[2] = cvt2(a1[0], a1[1]); r[3] = cvt2(a1[2], a1[3]);
  *(u32x4*)(dst + i8) = r;
}

// chol f32 -> LR bf16 (row-major, optional) + LT bf16 (transposed)
__global__ __launch_bounds__(256, 4)
void convert_LT_kernel(const float* __restrict__ chol,
                       unsigned short* __restrict__ LT,
                       unsigned short* __restrict__ LR) {
  __shared__ unsigned short T[64][72];
  const int bid = blockIdx.x;
  const int b  = bid >> 6;
  const int t  = bid & 63;
  const int ti = t >> 3, tj = t & 7;

  const float* src = chol + ((size_t)b * NV + ti * 64) * NV + tj * 64;
  {
    const int r0 = threadIdx.x >> 4;
    const int c4 = (threadIdx.x & 15) * 4;
    #pragma unroll
    for (int p = 0; p < 4; ++p) {
      const int r = p * 16 + r0;
      fv4 v = *(const fv4*)(src + (size_t)r * NV + c4);
      T[c4 + 0][r] = f2bf(v[0]);
      T[c4 + 1][r] = f2bf(v[1]);
      T[c4 + 2][r] = f2bf(v[2]);
      T[c4 + 3][r] = f2bf(v[3]);
      if (LR) {
        u32x2 pk; pk[0] = cvt2(v[0], v[1]); pk[1] = cvt2(v[2], v[3]);
        *(u32x2*)(LR + ((size_t)b * NV + ti * 64 + r) * NV + tj * 64 + c4) = pk;
      }
    }
  }
  __syncthreads();
  unsigned short* dst = LT + ((size_t)b * NV + tj * 64) * NV + ti * 64;
  const int c  = threadIdx.x >> 2;
  const int k8 = (threadIdx.x & 3) * 16;
  u16x8 o0, o1;
  #pragma unroll
  for (int q = 0; q < 8; ++q) { o0[q] = T[c][k8 + q]; o1[q] = T[c][k8 + 8 + q]; }
  *(u16x8*)(dst + (size_t)c * NV + k8)     = o0;
  *(u16x8*)(dst + (size_t)c * NV + k8 + 8) = o1;
}

// ---------------------------------------------------------------------------
// v14 main kernel: EXACT v11 K-loop and EXACT v11 5-barrier structure
// (v13's failure was a deleted read-drain barrier, not the prefetch).
// Cross-phase tile-0 prefetch is issued right after each phase's K-loop
// returns (buf is wave-private; its own reads are consumed), so the DMA
// hides under read-drain barrier + epilogue + ready barrier, and the
// barriers' vmcnt(0)-drain guarantees arrival.
// ---------------------------------------------------------------------------
__device__ __forceinline__ void stageA14(const unsigned short* A, int t, char* buf,
                                         int w, int lane) {
  const int row = lane >> 2;                       // 0..15 within 16-row chunk
  const int kq  = (lane & 3) ^ ((row >> 1) & 3);   // pre-swizzled source quarter
  #pragma unroll
  for (int pi = 0; pi < 4; ++pi) {
    const unsigned short* src = A + (size_t)(w * 64 + pi * 16 + row) * NV + t * 32 + kq * 8;
    gload_lds16(src, buf + pi * 1024);
  }
}

// tile 0 must already be staged (and drained by a barrier) by the caller.
__device__ __forceinline__ void phase_v14(const unsigned short* Abase,
                                          const char* H, char* buf,
                                          f32x4 (&acc0)[4][4], f32x4 (&acc1)[4][4],
                                          int w, int lane, int lr, int lq) {
  const int kqr = (lq ^ ((lr >> 1) & 3)) * 16;     // read-side swizzle
  #pragma unroll 2
  for (int t = 0; t < 16; ++t) {
    const int kbase = t * 32 + lq * 8;
    // wait own DMA (per-wave; no barrier). Trivially satisfied at t=0.
    asm volatile("s_waitcnt vmcnt(0)" ::: "memory");
    bf8 a[4];
    #pragma unroll
    for (int m = 0; m < 4; ++m)
      a[m] = *(const bf8*)(buf + (m * 16 + lr) * 64 + kqr);
    // issue next tile's DMA: after the A ds_reads, before the MFMA block
    if (t + 1 < 16) stageA14(Abase, t + 1, buf, w, lane);
    bf8 b0[4];
    #pragma unroll
    for (int n = 0; n < 4; ++n)
      b0[n] = *(const bf8*)(H + swzL(n * 16 + lr, kbase));
    bf8 b1[4];
    #pragma unroll
    for (int n = 0; n < 4; ++n)
      b1[n] = *(const bf8*)(H + swzL(64 + n * 16 + lr, kbase));
    __builtin_amdgcn_s_setprio(1);
    #pragma unroll
    for (int m = 0; m < 4; ++m)
      #pragma unroll
      for (int n = 0; n < 4; ++n)
        acc0[m][n] = __builtin_amdgcn_mfma_f32_16x16x32_bf16(a[m], b0[n], acc0[m][n], 0, 0, 0);
    #pragma unroll
    for (int m = 0; m < 4; ++m)
      #pragma unroll
      for (int n = 0; n < 4; ++n)
        acc1[m][n] = __builtin_amdgcn_mfma_f32_16x16x32_bf16(a[m], b1[n], acc1[m][n], 0, 0, 0);
    __builtin_amdgcn_s_setprio(0);
  }
}

__global__ __launch_bounds__(512, 2)
void fused_cholTE_v14(const unsigned short* __restrict__ CV,
                      const unsigned short* __restrict__ LR,
                      const unsigned short* __restrict__ LT,
                      float* __restrict__ out) {
  __shared__ __align__(16) char lds[163840];
  char* H = lds;                          // 128 cols x 1KB: cholC -> T1 -> phi

  const int tid  = threadIdx.x;
  const int w    = tid >> 6;              // wave 0..7
  const int lane = tid & 63;
  const int lr   = lane & 15;
  const int lq   = lane >> 4;
  char* buf = lds + 131072 + w * 4096;    // private per-wave A buffer

  const int bid = blockIdx.x;
  const int xcd = bid & 7;
  const int s   = bid >> 3;               // 0..63
  const int b   = xcd * 16 + (s >> 2);    // batch
  const int c0  = (s & 3) * 128;          // column pair base

  const unsigned short* CVb = CV + (size_t)b * NV * NV;
  const unsigned short* LRb = LR + (size_t)b * NV * NV;
  const unsigned short* LTb = LT + (size_t)b * NV * NV;
  float*                Ob  = out + (size_t)b * NV * NV;

  f32x4 acc0[4][4], acc1[4][4];

  // ---- stage both cholC panels + phase B's tile 0 (drained at barrier 1)
  #pragma unroll
  for (int cc = 0; cc < 16; ++cc) {
    const int c = cc * 8 + w;
    const unsigned short* src = LTb + (size_t)(c0 + c) * NV + ((lane ^ (c & 7)) * 8);
    gload_lds16(src, H + c * 1024);
  }
  stageA14(CVb, 0, buf, w, lane);
  asm volatile("s_waitcnt vmcnt(0)" ::: "memory");
  __syncthreads();   // barrier 1: cholC panels + B tile-0 ready

  // ---- Phase B: T1 = CV @ cholC
  #pragma unroll
  for (int m = 0; m < 4; ++m)
    #pragma unroll
    for (int n = 0; n < 4; ++n) { acc0[m][n] = (f32x4)0.f; acc1[m][n] = (f32x4)0.f; }
  phase_v14(CVb, H, buf, acc0, acc1, w, lane, lr, lq);

  // prefetch phase C's tile 0 into private buf (own loop's reads consumed;
  // DMA hides under barrier 2 + T1 epilogue + barrier 3, drained by them)
  stageA14(LTb, 0, buf, w, lane);
  __syncthreads();   // barrier 2: ALL waves done READING cholC (H)

  // T1 -> H (overwrite)
  #pragma unroll
  for (int m = 0; m < 4; ++m) {
    #pragma unroll
    for (int n = 0; n < 4; ++n) {
      const int rrow = w * 64 + m * 16 + lq * 4;
      f32x4 a = acc0[m][n];
      u32x2 pk; pk[0] = cvt2(a[0], a[1]); pk[1] = cvt2(a[2], a[3]);
      *(u32x2*)(H + swzL(n * 16 + lr, rrow)) = pk;
      a = acc1[m][n];
      pk[0] = cvt2(a[0], a[1]); pk[1] = cvt2(a[2], a[3]);
      *(u32x2*)(H + swzL(64 + n * 16 + lr, rrow)) = pk;
    }
  }
  __syncthreads();   // barrier 3: T1 panels ready (prefetch DMA drained)

  // ---- Phase C: phi = LT-rows @ T1 (masked)
  #pragma unroll
  for (int m = 0; m < 4; ++m)
    #pragma unroll
    for (int n = 0; n < 4; ++n) { acc0[m][n] = (f32x4)0.f; acc1[m][n] = (f32x4)0.f; }
  phase_v14(LTb, H, buf, acc0, acc1, w, lane, lr, lq);

  // prefetch phase D's tile 0
  stageA14(LRb, 0, buf, w, lane);
  __syncthreads();   // barrier 4: ALL waves done READING T1 (H)

  // mask (strict lower=1, diag=0.5, upper=0); phi -> H (overwrite)
  #pragma unroll
  for (int jt = 0; jt < 4; ++jt) {
    #pragma unroll
    for (int n = 0; n < 4; ++n) {
      const int j0 = w * 64 + jt * 16 + lq * 4;
      const int gk0 = c0 + n * 16 + lr;
      const int gk1 = gk0 + 64;
      f32x4 a = acc0[jt][n];
      float f[4];
      #pragma unroll
      for (int q = 0; q < 4; ++q) {
        const int j = j0 + q;
        f[q] = (j > gk0) ? a[q] : ((j == gk0) ? 0.5f * a[q] : 0.f);
      }
      u32x2 pk; pk[0] = cvt2(f[0], f[1]); pk[1] = cvt2(f[2], f[3]);
      *(u32x2*)(H + swzL(n * 16 + lr, j0)) = pk;
      a = acc1[jt][n];
      #pragma unroll
      for (int q = 0; q < 4; ++q) {
        const int j = j0 + q;
        f[q] = (j > gk1) ? a[q] : ((j == gk1) ? 0.5f * a[q] : 0.f);
      }
      pk[0] = cvt2(f[0], f[1]); pk[1] = cvt2(f[2], f[3]);
      *(u32x2*)(H + swzL(64 + n * 16 + lr, j0)) = pk;
    }
  }
  __syncthreads();   // barrier 5: phi panels ready (prefetch DMA drained)

  // ---- Phase D: out = -LR @ phi
  #pragma unroll
  for (int m = 0; m < 4; ++m)
    #pragma unroll
    for (int n = 0; n < 4; ++n) { acc0[m][n] = (f32x4)0.f; acc1[m][n] = (f32x4)0.f; }
  phase_v14(LRb, H, buf, acc0, acc1, w, lane, lr, lq);

  #pragma unroll
  for (int m = 0; m < 4; ++m) {
    const int i0 = w * 64 + m * 16 + lq * 4;
    #pragma unroll
    for (int n = 0; n < 4; ++n) {
      const int col = c0 + n * 16 + lr;
      f32x4 a = acc0[m][n];
      #pragma unroll
      for (int q = 0; q < 4; ++q)
        Ob[(size_t)(i0 + q) * NV + col] = -a[q];
      a = acc1[m][n];
      #pragma unroll
      for (int q = 0; q < 4; ++q)
        Ob[(size_t)(i0 + q) * NV + col + 64] = -a[q];
    }
  }
}

// ---------------------------------------------------------------------------
// v9 (LT-only path) for 64MB <= ws < 192MB
// ---------------------------------------------------------------------------
__device__ __forceinline__ void phase_v9_f32(const float* Abase,
                                             const char* H,
                                             f32x4 (&acc0)[4][4], f32x4 (&acc1)[4][4],
                                             int w, int lr, int lq) {
  const float* rA = Abase + (size_t)(w * 64 + lr) * NV + lq * 8;
  #pragma unroll 2
  for (int t = 0; t < 16; ++t) {
    const int kbase = t * 32 + lq * 8;
    bf8 a[4];
    #pragma unroll
    for (int m = 0; m < 4; ++m) {
      fv4 f0 = *(const fv4*)(rA + (size_t)(m * 16) * NV + t * 32);
      fv4 f1 = *(const fv4*)(rA + (size_t)(m * 16) * NV + t * 32 + 4);
      a[m] = pack8(f0, f1);
    }
    bf8 b0[4];
    #pragma unroll
    for (int n = 0; n < 4; ++n)
      b0[n] = *(const bf8*)(H + swzL(n * 16 + lr, kbase));
    #pragma unroll
    for (int m = 0; m < 4; ++m)
      #pragma unroll
      for (int n = 0; n < 4; ++n)
        acc0[m][n] = __builtin_amdgcn_mfma_f32_16x16x32_bf16(a[m], b0[n], acc0[m][n], 0, 0, 0);
    bf8 b1[4];
    #pragma unroll
    for (int n = 0; n < 4; ++n)
      b1[n] = *(const bf8*)(H + swzL(64 + n * 16 + lr, kbase));
    #pragma unroll
    for (int m = 0; m < 4; ++m)
      #pragma unroll
      for (int n = 0; n < 4; ++n)
        acc1[m][n] = __builtin_amdgcn_mfma_f32_16x16x32_bf16(a[m], b1[n], acc1[m][n], 0, 0, 0);
  }
}

__device__ __forceinline__ void phase_v9_bf16(const unsigned short* Abase,
                                              const char* H,
                                              f32x4 (&acc0)[4][4], f32x4 (&acc1)[4][4],
                                              int w, int lr, int lq) {
  const unsigned short* rA = Abase + (size_t)(w * 64 + lr) * NV + lq * 8;
  #pragma unroll 2
  for (int t = 0; t < 16; ++t) {
    const int kbase = t * 32 + lq * 8;
    bf8 a[4];
    #pragma unroll
    for (int m = 0; m < 4; ++m)
      a[m] = *(const bf8*)(rA + (size_t)(m * 16) * NV + t * 32);
    bf8 b0[4];
    #pragma unroll
    for (int n = 0; n < 4; ++n)
      b0[n] = *(const bf8*)(H + swzL(n * 16 + lr, kbase));
    #pragma unroll
    for (int m = 0; m < 4; ++m)
      #pragma unroll
      for (int n = 0; n < 4; ++n)
        acc0[m][n] = __builtin_amdgcn_mfma_f32_16x16x32_bf16(a[m], b0[n], acc0[m][n], 0, 0, 0);
    bf8 b1[4];
    #pragma unroll
    for (int n = 0; n < 4; ++n)
      b1[n] = *(const bf8*)(H + swzL(64 + n * 16 + lr, kbase));
    #pragma unroll
    for (int m = 0; m < 4; ++m)
      #pragma unroll
      for (int n = 0; n < 4; ++n)
        acc1[m][n] = __builtin_amdgcn_mfma_f32_16x16x32_bf16(a[m], b1[n], acc1[m][n], 0, 0, 0);
  }
}

__global__ __launch_bounds__(512, 2)
void fused_cholTE_v9(const float* __restrict__ covTE,
                     const float* __restrict__ chol,
                     const unsigned short* __restrict__ LT,
                     float* __restrict__ out) {
  __shared__ __align__(16) char H[131072];

  const int tid  = threadIdx.x;
  const int w    = tid >> 6;
  const int lane = tid & 63;
  const int lr   = lane & 15;
  const int lq   = lane >> 4;

  const int bid = blockIdx.x;
  const int xcd = bid & 7;
  const int s   = bid >> 3;
  const int b   = xcd * 16 + (s >> 2);
  const int c0  = (s & 3) * 128;

  const float*          Cb  = covTE + (size_t)b * NV * NV;
  const float*          Lb  = chol  + (size_t)b * NV * NV;
  const unsigned short* LTb = LT    + (size_t)b * NV * NV;
  float*                Ob  = out   + (size_t)b * NV * NV;

  f32x4 acc0[4][4], acc1[4][4];

  #pragma unroll
  for (int cc = 0; cc < 16; ++cc) {
    const int c = cc * 8 + w;
    const unsigned short* src = LTb + (size_t)(c0 + c) * NV + ((lane ^ (c & 7)) * 8);
    gload_lds16(src, H + c * 1024);
  }
  asm volatile("s_waitcnt vmcnt(0)" ::: "memory");
  __syncthreads();

  #pragma unroll
  for (int m = 0; m < 4; ++m)
    #pragma unroll
    for (int n = 0; n < 4; ++n) { acc0[m][n] = (f32x4)0.f; acc1[m][n] = (f32x4)0.f; }
  phase_v9_f32(Cb, H, acc0, acc1, w, lr, lq);
  __syncthreads();

  #pragma unroll
  for (int m = 0; m < 4; ++m) {
    #pragma unroll
    for (int n = 0; n < 4; ++n) {
      const int rrow = w * 64 + m * 16 + lq * 4;
      f32x4 a = acc0[m][n];
      u32x2 pk; pk[0] = cvt2(a[0], a[1]); pk[1] = cvt2(a[2], a[3]);
      *(u32x2*)(H + swzL(n * 16 + lr, rrow)) = pk;
      a = acc1[m][n];
      pk[0] = cvt2(a[0], a[1]); pk[1] = cvt2(a[2], a[3]);
      *(u32x2*)(H + swzL(64 + n * 16 + lr, rrow)) = pk;
    }
  }
  __syncthreads();

  #pragma unroll
  for (int m = 0; m < 4; ++m)
    #pragma unroll
    for (int n = 0; n < 4; ++n) { acc0[m][n] = (f32x4)0.f; acc1[m][n] = (f32x4)0.f; }
  phase_v9_bf16(LTb, H, acc0, acc1, w, lr, lq);
  __syncthreads();

  #pragma unroll
  for (int jt = 0; jt < 4; ++jt) {
    #pragma unroll
    for (int n = 0; n < 4; ++n) {
      const int j0 = w * 64 + jt * 16 + lq * 4;
      const int gk0 = c0 + n * 16 + lr;
      const int gk1 = gk0 + 64;
      f32x4 a = acc0[jt][n];
      float f[4];
      #pragma unroll
      for (int q = 0; q < 4; ++q) {
        const int j = j0 + q;
        f[q] = (j > gk0) ? a[q] : ((j == gk0) ? 0.5f * a[q] : 0.f);
      }
      u32x2 pk; pk[0] = cvt2(f[0], f[1]); pk[1] = cvt2(f[2], f[3]);
      *(u32x2*)(H + swzL(n * 16 + lr, j0)) = pk;
      a = acc1[jt][n];
      #pragma unroll
      for (int q = 0; q < 4; ++q) {
        const int j = j0 + q;
        f[q] = (j > gk1) ? a[q] : ((j == gk1) ? 0.5f * a[q] : 0.f);
      }
      pk[0] = cvt2(f[0], f[1]); pk[1] = cvt2(f[2], f[3]);
      *(u32x2*)(H + swzL(64 + n * 16 + lr, j0)) = pk;
    }
  }
  __syncthreads();

  #pragma unroll
  for (int m = 0; m < 4; ++m)
    #pragma unroll
    for (int n = 0; n < 4; ++n) { acc0[m][n] = (f32x4)0.f; acc1[m][n] = (f32x4)0.f; }
  phase_v9_f32(Lb, H, acc0, acc1, w, lr, lq);

  #pragma unroll
  for (int m = 0; m < 4; ++m) {
    const int i0 = w * 64 + m * 16 + lq * 4;
    #pragma unroll
    for (int n = 0; n < 4; ++n) {
      const int col = c0 + n * 16 + lr;
      f32x4 a = acc0[m][n];
      #pragma unroll
      for (int q = 0; q < 4; ++q)
        Ob[(size_t)(i0 + q) * NV + col] = -a[q];
      a = acc1[m][n];
      #pragma unroll
      for (int q = 0; q < 4; ++q)
        Ob[(size_t)(i0 + q) * NV + col + 64] = -a[q];
    }
  }
}

// ---------------------------------------------------------------------------
// No-workspace fallback (R1 form)
// ---------------------------------------------------------------------------
__global__ __launch_bounds__(1024, 1)
void fused_cholTE_fallback(const float* __restrict__ covTE,
                           const float* __restrict__ chol,
                           float* __restrict__ out) {
  __shared__ __align__(16) char lds[131072];
  char* sB0 = lds;
  char* sB1 = lds + 65536;
  char* sCh = lds;

  const int tid  = threadIdx.x;
  const int w    = tid >> 6;
  const int lane = tid & 63;
  const int lr   = lane & 15;
  const int lq   = lane >> 4;

  const int bid = blockIdx.x;
  const int xcd = bid & 7;
  const int s   = bid >> 3;
  const int b   = xcd * 16 + (s >> 3);
  const int c0  = (s & 7) * NC;

  const float* Cb = covTE + (size_t)b * NV * NV;
  const float* Lb = chol  + (size_t)b * NV * NV;
  float*       Ob = out   + (size_t)b * NV * NV;

  {
    const int rr = tid >> 4;
    const int cc = (tid & 15) * 4;
    #pragma unroll
    for (int p = 0; p < 8; ++p) {
      const int r = p * 64 + rr;
      fv4 v = *(const fv4*)(Lb + (size_t)r * NV + c0 + cc);
      *(unsigned short*)(sB0 + swzL(cc + 0, r)) = f2bf(v[0]);
      *(unsigned short*)(sB0 + swzL(cc + 1, r)) = f2bf(v[1]);
      *(unsigned short*)(sB0 + swzL(cc + 2, r)) = f2bf(v[2]);
      *(unsigned short*)(sB0 + swzL(cc + 3, r)) = f2bf(v[3]);
    }
  }
  __syncthreads();

  f32x4 acc[2][4];
  #pragma unroll
  for (int m = 0; m < 2; ++m)
    #pragma unroll
    for (int n = 0; n < 4; ++n) acc[m][n] = (f32x4)0.f;

  for (int kb = 0; kb < 16; ++kb) {
    const int kbase = kb * 32 + lq * 8;
    bf8 bfr[4];
    #pragma unroll
    for (int n = 0; n < 4; ++n)
      bfr[n] = *(const bf8*)(sB0 + swzL(n * 16 + lr, kbase));
    #pragma unroll
    for (int m = 0; m < 2; ++m) {
      const float* p = Cb + (size_t)(w * 32 + m * 16 + lr) * NV + kbase;
      fv4 a0 = *(const fv4*)p;
      fv4 a1 = *(const fv4*)(p + 4);
      bf8 af = pack8(a0, a1);
      #pragma unroll
      for (int n = 0; n < 4; ++n)
        acc[m][n] = __builtin_amdgcn_mfma_f32_16x16x32_bf16(af, bfr[n], acc[m][n], 0, 0, 0);
    }
  }
  #pragma unroll
  for (int m = 0; m < 2; ++m) {
    #pragma unroll
    for (int n = 0; n < 4; ++n) {
      f32x4 a = acc[m][n];
      u32x2 pk; pk[0] = cvt2(a[0], a[1]); pk[1] = cvt2(a[2], a[3]);
      *(u32x2*)(sB1 + swzL(n * 16 + lr, w * 32 + m * 16 + lq * 4)) = pk;
    }
  }
  __syncthreads();

  #pragma unroll
  for (int m = 0; m < 2; ++m)
    #pragma unroll
    for (int n = 0; n < 4; ++n) acc[m][n] = (f32x4)0.f;

  const int sj = (tid & 255) * 2;
  const int so = tid >> 8;

  fv2 raw[8];
  {
    const float* src = Lb + (size_t)(so * 8) * NV + sj;
    #pragma unroll
    for (int r = 0; r < 8; ++r) raw[r] = *(const fv2*)(src + (size_t)r * NV);
    u16x8 p0, p1;
    #pragma unroll
    for (int r = 0; r < 8; ++r) { p0[r] = f2bf(raw[r][0]); p1[r] = f2bf(raw[r][1]); }
    *(u16x8*)(sCh + swzC(sj + 0, so * 8)) = p0;
    *(u16x8*)(sCh + swzC(sj + 1, so * 8)) = p1;
  }
  __syncthreads();

  for (int ib = 0; ib < 16; ++ib) {
    if (ib + 1 < 16) {
      const float* src = Lb + (size_t)((ib + 1) * 32 + so * 8) * NV + sj;
      #pragma unroll
      for (int r = 0; r < 8; ++r) raw[r] = *(const fv2*)(src + (size_t)r * NV);
    }
    bf8 bt[4];
    #pragma unroll
    for (int n = 0; n < 4; ++n)
      bt[n] = *(const bf8*)(sB1 + swzL(n * 16 + lr, ib * 32 + lq * 8));
    #pragma unroll
    for (int jt = 0; jt < 2; ++jt) {
      bf8 af = *(const bf8*)(sCh + swzC(w * 32 + jt * 16 + lr, lq * 8));
      #pragma unroll
      for (int n = 0; n < 4; ++n)
        acc[jt][n] = __builtin_amdgcn_mfma_f32_16x16x32_bf16(af, bt[n], acc[jt][n], 0, 0, 0);
    }
    __syncthreads();
    if (ib + 1 < 16) {
      u16x8 p0, p1;
      #pragma unroll
      for (int r = 0; r < 8; ++r) { p0[r] = f2bf(raw[r][0]); p1[r] = f2bf(raw[r][1]); }
      *(u16x8*)(sCh + swzC(sj + 0, so * 8)) = p0;
      *(u16x8*)(sCh + swzC(sj + 1, so * 8)) = p1;
    }
    __syncthreads();
  }

  #pragma unroll
  for (int jt = 0; jt < 2; ++jt) {
    #pragma unroll
    for (int n = 0; n < 4; ++n) {
      f32x4 a = acc[jt][n];
      const int gk = c0 + n * 16 + lr;
      const int j0 = w * 32 + jt * 16 + lq * 4;
      float f[4];
      #pragma unroll
      for (int q = 0; q < 4; ++q) {
        const int j = j0 + q;
        f[q] = (j > gk) ? a[q] : ((j == gk) ? 0.5f * a[q] : 0.f);
      }
      u32x2 pk; pk[0] = cvt2(f[0], f[1]); pk[1] = cvt2(f[2], f[3]);
      *(u32x2*)(sB0 + swzL(n * 16 + lr, j0)) = pk;
    }
  }
  __syncthreads();

  #pragma unroll
  for (int m = 0; m < 2; ++m)
    #pragma unroll
    for (int n = 0; n < 4; ++n) acc[m][n] = (f32x4)0.f;

  for (int kb = 0; kb < 16; ++kb) {
    const int kbase = kb * 32 + lq * 8;
    bf8 bp[4];
    #pragma unroll
    for (int n = 0; n < 4; ++n)
      bp[n] = *(const bf8*)(sB0 + swzL(n * 16 + lr, kbase));
    #pragma unroll
    for (int m = 0; m < 2; ++m) {
      const float* p = Lb + (size_t)(w * 32 + m * 16 + lr) * NV + kbase;
      fv4 a0 = *(const fv4*)p;
      fv4 a1 = *(const fv4*)(p + 4);
      bf8 af = pack8(a0, a1);
      #pragma unroll
      for (int n = 0; n < 4; ++n)
        acc[m][n] = __builtin_amdgcn_mfma_f32_16x16x32_bf16(af, bp[n], acc[m][n], 0, 0, 0);
    }
  }
  #pragma unroll
  for (int m = 0; m < 2; ++m) {
    const int i0 = w * 32 + m * 16 + lq * 4;
    #pragma unroll
    for (int n = 0; n < 4; ++n) {
      f32x4 a = acc[m][n];
      const int col = c0 + n * 16 + lr;
      #pragma unroll
      for (int q = 0; q < 4; ++q)
        Ob[(size_t)(i0 + q) * NV + col] = -a[q];
    }
  }
}

extern "C" void kernel_launch(void* const* d_in, const int* in_sizes, int n_in,
                              void* d_out, int out_size, void* d_ws, size_t ws_size,
                              hipStream_t stream) {
  const float* muTE  = (const float*)d_in[0];
  const float* covTE = (const float*)d_in[1];
  const float* chol  = (const float*)d_in[2];
  float* out = (float*)d_out;

  (void)hipMemcpyAsync(out, muTE, (size_t)NB * NV * sizeof(float),
                       hipMemcpyDeviceToDevice, stream);

  float* cholTE = out + (size_t)NB * NV;
  const size_t nmat     = (size_t)NB * NV * NV;          // 33,554,432 elems
  const size_t lt_bytes = nmat * sizeof(unsigned short); // 64 MiB

  if (ws_size >= 3 * lt_bytes) {
    unsigned short* CV = (unsigned short*)d_ws;
    unsigned short* LR = CV + nmat;
    unsigned short* LT = LR + nmat;
    conv_f32_bf16_kernel<<<dim3(nmat / (256 * 8)), dim3(256), 0, stream>>>(covTE, CV);
    convert_LT_kernel<<<dim3(NB * 64), dim3(256), 0, stream>>>(chol, LT, LR);
    fused_cholTE_v14<<<dim3(NB * 4), dim3(512), 0, stream>>>(CV, LR, LT, cholTE);
  } else if (ws_size >= lt_bytes) {
    unsigned short* LT = (unsigned short*)d_ws;
    convert_LT_kernel<<<dim3(NB * 64), dim3(256), 0, stream>>>(chol, LT, nullptr);
    fused_cholTE_v9<<<dim3(NB * 4), dim3(512), 0, stream>>>(covTE, chol, LT, cholTE);
  } else {
    fused_cholTE_fallback<<<dim3(NB * (NV / NC)), dim3(1024), 0, stream>>>(
        covTE, chol, cholTE);
  }
}